// Round 19
// baseline (200.086 us; speedup 1.0000x reference)
//
#include <hip/hip_runtime.h>
#include <hip/hip_bf16.h>

// ---------------- problem constants ----------------
#define BATCH   32768
#define DIM     512
#define H1N     128
#define H2N     256
#define NSUB    20
#define HID     32
#define NCLS    100
#define NHID    640            // NSUB*HID
#define TOTALP  19716          // 512*32 + 32 + 32*100 + 100
#define NPAR    394320         // NSUB*TOTALP
#define WS1P    16384
#define WS1B1   16416          // WS1+BS1
#define WS2END  19616          // WS1+BS1+WS2

// ---------------- ws layout (float units) ----------------
#define OFF_PART 0              // 512*512 partial col sums
#define OFF_H    262144         // 256 f32 hypernet h
#define OFF_W    262400         // 32 f32 softmax(ens_w)
#define OFF_B1   262432         // 640 f32
#define OFF_B2R  263072         // 2000 f32 raw b2
#define OFF_W1B  265072         // bf16 640*512   (163840 f32 slots)
#define OFF_W2B  428912         // bf16 128*640   (40960 f32 slots)
#define OFF_PRED 470000         // 8*512 f32 pre-reduced partials

typedef __attribute__((ext_vector_type(8))) short short8;
typedef __attribute__((ext_vector_type(4))) float f32x4;

static __device__ inline unsigned short f2bf(float f) {
    __hip_bfloat16 h = __float2bfloat16(f);
    return *reinterpret_cast<unsigned short*>(&h);
}

static __device__ __forceinline__ void gload16(const void* g, void* l) {
    __builtin_amdgcn_global_load_lds(
        (const __attribute__((address_space(1))) void*)g,
        (__attribute__((address_space(3))) void*)l, 16, 0, 0);
}

// ---------------- K1: partial column sums of x (pure, no convert) -----------
__global__ __launch_bounds__(256) void k1_colsum(const float* __restrict__ x,
                                                 float* __restrict__ F) {
    __shared__ float sP[DIM];
    int t = threadIdx.x, bid = blockIdx.x;
    int par = t >> 7;            // 0 or 1
    int c4 = (t & 127) * 4;
    const float* xb = x + (size_t)bid * 64 * DIM;
    float4 acc = make_float4(0.f, 0.f, 0.f, 0.f);
    #pragma unroll 8
    for (int i = 0; i < 32; ++i) {
        int r = 2 * i + par;
        float4 v = *(const float4*)(xb + r * DIM + c4);
        acc.x += v.x; acc.y += v.y; acc.z += v.z; acc.w += v.w;
    }
    if (par == 0) *(float4*)(sP + c4) = acc;
    __syncthreads();
    if (par == 1) {
        float4 p = *(const float4*)(sP + c4);
        p.x += acc.x; p.y += acc.y; p.z += acc.z; p.w += acc.w;
        *(float4*)(F + OFF_PART + bid * DIM + c4) = p;
    }
}

// ---------------- K1b: pre-reduce 512 partial rows -> 8 ----------------------
__global__ __launch_bounds__(256) void k1b_red(float* __restrict__ F) {
    int bx = blockIdx.x;               // 16 blocks
    int orow = bx >> 1;
    int c = (bx & 1) * 256 + threadIdx.x;
    float s = 0.f;
    #pragma unroll 8
    for (int j = 0; j < 64; ++j)
        s += F[OFF_PART + (orow * 64 + j) * DIM + c];
    F[OFF_PRED + orow * DIM + c] = s;
}

// ---------------- K2: hypernet trunk (1 block) ----------
__global__ __launch_bounds__(256) void k2_hyper(
    const float* __restrict__ Wh1, const float* __restrict__ bh1,
    const float* __restrict__ g1,  const float* __restrict__ be1,
    const float* __restrict__ Wh2, const float* __restrict__ bh2,
    const float* __restrict__ g2,  const float* __restrict__ be2,
    const float* __restrict__ ensw, float* __restrict__ F)
{
    __shared__ __align__(16) float sctx[DIM];
    __shared__ __align__(16) float sh1[H1N];
    __shared__ __align__(16) float sh2[H2N];
    int t = threadIdx.x;

    if (t < 128) {
        int c4 = t * 4;
        float4 a = make_float4(0.f, 0.f, 0.f, 0.f);
        #pragma unroll
        for (int b = 0; b < 8; ++b) {
            float4 v = *(const float4*)(F + OFF_PRED + b * DIM + c4);
            a.x += v.x; a.y += v.y; a.z += v.z; a.w += v.w;
        }
        a.x *= (1.0f / BATCH); a.y *= (1.0f / BATCH);
        a.z *= (1.0f / BATCH); a.w *= (1.0f / BATCH);
        *(float4*)(sctx + c4) = a;
    }
    __syncthreads();

    if (t < H1N) {
        float v = bh1[t];
        const float4* w = (const float4*)(Wh1 + t * DIM);
        for (int k = 0; k < DIM / 4; ++k) {
            float4 ww = w[k]; float4 c = *(const float4*)(sctx + k * 4);
            v += ww.x * c.x + ww.y * c.y + ww.z * c.z + ww.w * c.w;
        }
        sh1[t] = v;
    }
    __syncthreads();
    {
        float mu = 0.f;
        for (int k = 0; k < H1N; ++k) mu += sh1[k];
        mu *= (1.0f / H1N);
        float var = 0.f;
        for (int k = 0; k < H1N; ++k) { float d = sh1[k] - mu; var += d * d; }
        var *= (1.0f / H1N);
        float inv = rsqrtf(var + 1e-5f);
        __syncthreads();
        if (t < H1N) {
            float v = (sh1[t] - mu) * inv * g1[t] + be1[t];
            sh1[t] = fmaxf(v, 0.f);
        }
        __syncthreads();
    }

    {
        float v = bh2[t];
        const float4* w = (const float4*)(Wh2 + t * H1N);
        for (int k = 0; k < H1N / 4; ++k) {
            float4 ww = w[k]; float4 c = *(const float4*)(sh1 + k * 4);
            v += ww.x * c.x + ww.y * c.y + ww.z * c.z + ww.w * c.w;
        }
        sh2[t] = v;
    }
    __syncthreads();
    {
        float mu = 0.f;
        for (int k = 0; k < H2N; ++k) mu += sh2[k];
        mu *= (1.0f / H2N);
        float var = 0.f;
        for (int k = 0; k < H2N; ++k) { float d = sh2[k] - mu; var += d * d; }
        var *= (1.0f / H2N);
        float inv = rsqrtf(var + 1e-5f);
        float v = (sh2[t] - mu) * inv * g2[t] + be2[t];
        F[OFF_H + t] = fmaxf(v, 0.f);
    }

    if (t == 0) {
        float m = -1e30f;
        for (int s = 0; s < NSUB; ++s) m = fmaxf(m, ensw[s]);
        float sum = 0.f, e[NSUB];
        for (int s = 0; s < NSUB; ++s) { e[s] = __expf(ensw[s] - m); sum += e[s]; }
        for (int s = 0; s < NSUB; ++s) F[OFF_W + s] = e[s] / sum;
    }
}

// ---------------- K3: persistent grid-stride GEMV + pack ---------------------
static __device__ __forceinline__ void k3_pack(float* F, int row, float val) {
    __hip_bfloat16* W1B = (__hip_bfloat16*)(F + OFF_W1B);
    __hip_bfloat16* W2B = (__hip_bfloat16*)(F + OFF_W2B);
    int s = row / TOTALP;
    int r = row - s * TOTALP;
    if (r < WS1P) {
        int hh = r >> 9, k = r & 511;
        W1B[(s * HID + hh) * DIM + k] = __float2bfloat16(val);
    } else if (r < WS1B1) {
        F[OFF_B1 + s * HID + (r - WS1P)] = val;
    } else if (r < WS2END) {
        int q = r - WS1B1; int c = q >> 5, hh = q & 31;
        float ws = F[OFF_W + s];
        W2B[c * NHID + s * HID + hh] = __float2bfloat16(ws * val);
    } else {
        F[OFF_B2R + s * NCLS + (r - WS2END)] = val;
    }
}

#define K3_NWAVE 8192
#define K3_STRIDE (K3_NWAVE * 2)      // 16384 rows per sweep

__global__ __launch_bounds__(256) void k3_gemv(
    const float* __restrict__ Wh3, const float* __restrict__ bh3, float* __restrict__ F)
{
    int t = threadIdx.x;
    int wid = t >> 6, lane = t & 63;
    int gw = blockIdx.x * 4 + wid;
    const float4 h = *(const float4*)(F + OFF_H + lane * 4);

    int row = gw * 2;
    float4 w0, w1;
    if (row < NPAR) {
        w0 = *(const float4*)(Wh3 + (size_t)row * 256 + lane * 4);
        w1 = *(const float4*)(Wh3 + (size_t)(row + 1) * 256 + lane * 4);
    }
    while (row < NPAR) {
        int nrow = row + K3_STRIDE;
        float4 n0, n1;
        if (nrow < NPAR) {
            n0 = *(const float4*)(Wh3 + (size_t)nrow * 256 + lane * 4);
            n1 = *(const float4*)(Wh3 + (size_t)(nrow + 1) * 256 + lane * 4);
        }
        float d0 = w0.x * h.x + w0.y * h.y + w0.z * h.z + w0.w * h.w;
        float d1 = w1.x * h.x + w1.y * h.y + w1.z * h.z + w1.w * h.w;
        #pragma unroll
        for (int off = 32; off; off >>= 1) {
            d0 += __shfl_down(d0, off);
            d1 += __shfl_down(d1, off);
        }
        if (lane == 0) {
            k3_pack(F, row,     d0 + bh3[row]);
            k3_pack(F, row + 1, d1 + bh3[row + 1]);
        }
        w0 = n0; w1 = n1;
        row = nrow;
    }
}

// ---------------- K5: fused dual GEMM, A-in-reg, BK=128, T4 pipeline ---------
// BM=64, 4 waves (1x8 tile). afr[16] holds the wave's 16 rows x K=512.
// 25 phases: per chunk n1: st=0..3 stage-1 K-steps (BK=128), st=4 = full W2
// chunk (128 rows x 128 k, 32 KB). Every phase stages 8 gload16/thread ->
// uniform vmcnt(8) counted waits; vmcnt(0) only at the final phase.
// LDS: sB 2x32KB + sP 16KB = 80 KB -> 2 blocks/CU.
__global__ __launch_bounds__(256) void gemm_fused(
    const float* __restrict__ x, const __hip_bfloat16* __restrict__ W1B,
    const __hip_bfloat16* __restrict__ W2B, const float* __restrict__ F,
    float* __restrict__ out)
{
    __shared__ __align__(16) unsigned char sB[2][128 * 256];   // 2 x 32 KB
    __shared__ __align__(16) unsigned char sP[64 * 256];       // 16 KB
    const int t = threadIdx.x;
    int bid = blockIdx.x;
    const int cpx = gridDim.x >> 3;
    bid = (bid & 7) * cpx + (bid >> 3);
    const int Row0 = bid * 64;
    const int wid = t >> 6, lane = t & 63;
    const int l16 = lane & 15, lq = lane >> 4;

    f32x4 acc1[8], acc2[8];
    #pragma unroll
    for (int fn = 0; fn < 8; ++fn) acc2[fn] = (f32x4){0.f, 0.f, 0.f, 0.f};

    // stage-1 W1B tile: 128 rows x 128 k (32 KB), 8 units/thread (R8 layout)
    auto stageW1 = [&](int n1, int kc, int b) {
        #pragma unroll
        for (int i = 0; i < 8; ++i) {
            int ul = (wid * 8 + i) * 64 + lane;
            int row = ul >> 4, u = ul & 15;
            gload16(W1B + (size_t)(n1 * 128 + row) * 512 + kc + ((u ^ (row & 7)) << 3),
                    &sB[b][(wid * 8 + i) * 1024]);
        }
    };
    // W2 chunk: 128 rows x 128 k (32 KB), one phase
    auto stageW2 = [&](int n1, int b) {
        #pragma unroll
        for (int i = 0; i < 8; ++i) {
            int ul = (wid * 8 + i) * 64 + lane;
            int row = ul >> 4, u = ul & 15;
            gload16(W2B + (size_t)row * NHID + n1 * 128 + ((u ^ (row & 7)) << 3),
                    &sB[b][(wid * 8 + i) * 1024]);
        }
    };

    stageW1(0, 0, 0);

    short8 afr[16];                    // A fragments, whole K; 64 VGPR
    {
        const float* xrow = x + (size_t)(Row0 + wid * 16 + l16) * 512;
        #pragma unroll
        for (int i = 0; i < 16; ++i) { // k0 = i*32 + lq*8
            int k0 = i * 32 + lq * 8;
            float4 a = *(const float4*)(xrow + k0);
            float4 b = *(const float4*)(xrow + k0 + 4);
            unsigned int p[4];
            p[0] = (unsigned)f2bf(a.x) | ((unsigned)f2bf(a.y) << 16);
            p[1] = (unsigned)f2bf(a.z) | ((unsigned)f2bf(a.w) << 16);
            p[2] = (unsigned)f2bf(b.x) | ((unsigned)f2bf(b.y) << 16);
            p[3] = (unsigned)f2bf(b.z) | ((unsigned)f2bf(b.w) << 16);
            afr[i] = *(short8*)p;
        }
    }
    asm volatile("s_waitcnt vmcnt(0)" ::: "memory");
    __builtin_amdgcn_s_barrier();

    // comp1: one BK=128 step; kk = 0..3; af = afr[st*4+kk]
    auto comp1 = [&](int st, int b) {
        #pragma unroll
        for (int kk = 0; kk < 4; ++kk) {
            int u = kk * 4 + lq;
            short8 af = afr[st * 4 + kk];
            short8 bfv[8];
            #pragma unroll
            for (int fn = 0; fn < 8; ++fn) {
                int rw = fn * 16 + l16;
                bfv[fn] = *(const short8*)(&sB[b][rw * 256 + ((u ^ (rw & 7)) << 4)]);
            }
            #pragma unroll
            for (int fn = 0; fn < 8; ++fn)
                acc1[fn] = __builtin_amdgcn_mfma_f32_16x16x32_bf16(
                    af, bfv[fn], acc1[fn], 0, 0, 0);
        }
    };
    // comp2: full K=128 of the W2 chunk in one phase
    auto comp2 = [&](int b) {
        #pragma unroll
        for (int kk = 0; kk < 4; ++kk) {
            int u = kk * 4 + lq;
            int arow = wid * 16 + l16;
            short8 af = *(const short8*)(&sP[arow * 256 + ((u ^ (arow & 7)) << 4)]);
            short8 bfv[8];
            #pragma unroll
            for (int fn = 0; fn < 8; ++fn) {
                int rw = fn * 16 + l16;
                bfv[fn] = *(const short8*)(&sB[b][rw * 256 + ((u ^ (rw & 7)) << 4)]);
            }
            #pragma unroll
            for (int fn = 0; fn < 8; ++fn)
                acc2[fn] = __builtin_amdgcn_mfma_f32_16x16x32_bf16(
                    af, bfv[fn], acc2[fn], 0, 0, 0);
        }
    };

    // ---- pipeline: 25 phases (5 per chunk: 4x stage-1 + 1x W2) ----
    int buf = 0;
    float b1r[8];
    for (int p = 0; p < 25; ++p) {
        int n1 = p / 5, st = p % 5;
        // issue stage for next phase
        if (p < 24) {
            int np = p + 1, nn1 = np / 5, nst = np % 5;
            if (nst < 4) stageW1(nn1, nst * 128, buf ^ 1);
            else stageW2(nn1, buf ^ 1);
        }
        if (p < 24) asm volatile("s_waitcnt vmcnt(8)" ::: "memory");
        else        asm volatile("s_waitcnt vmcnt(0)" ::: "memory");
        __builtin_amdgcn_s_barrier();
        __builtin_amdgcn_sched_barrier(0);

        if (st == 0) {
            #pragma unroll
            for (int fn = 0; fn < 8; ++fn) {
                acc1[fn] = (f32x4){0.f, 0.f, 0.f, 0.f};
                b1r[fn] = F[OFF_B1 + n1 * 128 + fn * 16 + l16];
            }
        }
        if (st < 4) comp1(st, buf);
        else comp2(buf);
        if (st == 3) {
            // pack: P = relu(acc1+b1) -> bf16 -> sP (wave-private rows)
            #pragma unroll
            for (int fn = 0; fn < 8; ++fn) {
                int col = fn * 16 + l16;
                int unit = col >> 3;
                #pragma unroll
                for (int r = 0; r < 4; ++r) {
                    int row = wid * 16 + lq * 4 + r;
                    float v = fmaxf(acc1[fn][r] + b1r[fn], 0.f);
                    *(unsigned short*)(&sP[row * 256 + ((unit ^ (row & 7)) << 4)
                                       + (col & 7) * 2]) = f2bf(v);
                }
            }
        }
        __builtin_amdgcn_sched_barrier(0);
        __builtin_amdgcn_s_barrier();
        buf ^= 1;
    }

    float* sBe = (float*)sP;
    if (t < 128) {
        float b = 0.f;
        if (t < NCLS) {
            #pragma unroll
            for (int s = 0; s < NSUB; ++s)
                b += F[OFF_W + s] * F[OFF_B2R + s * NCLS + t];
        }
        sBe[t] = b;
    }
    __syncthreads();

    #pragma unroll
    for (int fn = 0; fn < 8; ++fn) {
        int gcol = fn * 16 + l16;
        if (gcol < NCLS) {
            float be = sBe[gcol];
            #pragma unroll
            for (int r = 0; r < 4; ++r) {
                int grow = Row0 + wid * 16 + lq * 4 + r;
                out[(size_t)grow * NCLS + gcol] = acc2[fn][r] + be;
            }
        }
    }
}

// ---------------- launch ----------------
extern "C" void kernel_launch(void* const* d_in, const int* in_sizes, int n_in,
                              void* d_out, int out_size, void* d_ws, size_t ws_size,
                              hipStream_t stream)
{
    const float* x    = (const float*)d_in[0];
    const float* Wh1  = (const float*)d_in[1];
    const float* bh1  = (const float*)d_in[2];
    const float* g1   = (const float*)d_in[3];
    const float* be1  = (const float*)d_in[4];
    const float* Wh2  = (const float*)d_in[5];
    const float* bh2  = (const float*)d_in[6];
    const float* g2   = (const float*)d_in[7];
    const float* be2  = (const float*)d_in[8];
    const float* Wh3  = (const float*)d_in[9];
    const float* bh3  = (const float*)d_in[10];
    const float* ensw = (const float*)d_in[11];
    float* F = (float*)d_ws;
    float* out = (float*)d_out;

    const __hip_bfloat16* W1B = (const __hip_bfloat16*)(F + OFF_W1B);
    const __hip_bfloat16* W2B = (const __hip_bfloat16*)(F + OFF_W2B);

    k1_colsum<<<512, 256, 0, stream>>>(x, F);
    k1b_red<<<16, 256, 0, stream>>>(F);
    k2_hyper<<<1, 256, 0, stream>>>(Wh1, bh1, g1, be1, Wh2, bh2, g2, be2, ensw, F);
    k3_gemv<<<2048, 256, 0, stream>>>(Wh3, bh3, F);
    // fused: out = relu(x@W1^T+b1) @ W2^T + be   M=32768, grid 512 x BM=64
    gemm_fused<<<BATCH / 64, 256, 0, stream>>>(x, W1B, W2B, F, out);
}

// Round 20
// 177.494 us; speedup vs baseline: 1.1273x; 1.1273x over previous
//
#include <hip/hip_runtime.h>
#include <hip/hip_bf16.h>

// ---------------- problem constants ----------------
#define BATCH   32768
#define DIM     512
#define H1N     128
#define H2N     256
#define NSUB    20
#define HID     32
#define NCLS    100
#define NHID    640            // NSUB*HID
#define TOTALP  19716          // 512*32 + 32 + 32*100 + 100
#define NPAR    394320         // NSUB*TOTALP
#define WS1P    16384
#define WS1B1   16416          // WS1+BS1
#define WS2END  19616          // WS1+BS1+WS2

// ---------------- ws layout (float units) ----------------
#define OFF_PART 0              // 512*512 partial col sums
#define OFF_H    262144         // 256 f32 hypernet h
#define OFF_W    262400         // 32 f32 softmax(ens_w)
#define OFF_B1   262432         // 640 f32
#define OFF_B2R  263072         // 2000 f32 raw b2
#define OFF_W1B  265072         // bf16 640*512   (163840 f32 slots)
#define OFF_W2B  428912         // bf16 128*640   (40960 f32 slots)
#define OFF_PRED 470000         // 8*512 f32 pre-reduced partials

typedef __attribute__((ext_vector_type(8))) short short8;
typedef __attribute__((ext_vector_type(4))) float f32x4;

static __device__ inline unsigned short f2bf(float f) {
    __hip_bfloat16 h = __float2bfloat16(f);
    return *reinterpret_cast<unsigned short*>(&h);
}

static __device__ __forceinline__ void gload16(const void* g, void* l) {
    __builtin_amdgcn_global_load_lds(
        (const __attribute__((address_space(1))) void*)g,
        (__attribute__((address_space(3))) void*)l, 16, 0, 0);
}

// ---------------- K1: partial column sums of x (pure, no convert) -----------
__global__ __launch_bounds__(256) void k1_colsum(const float* __restrict__ x,
                                                 float* __restrict__ F) {
    __shared__ float sP[DIM];
    int t = threadIdx.x, bid = blockIdx.x;
    int par = t >> 7;            // 0 or 1
    int c4 = (t & 127) * 4;
    const float* xb = x + (size_t)bid * 64 * DIM;
    float4 acc = make_float4(0.f, 0.f, 0.f, 0.f);
    #pragma unroll 8
    for (int i = 0; i < 32; ++i) {
        int r = 2 * i + par;
        float4 v = *(const float4*)(xb + r * DIM + c4);
        acc.x += v.x; acc.y += v.y; acc.z += v.z; acc.w += v.w;
    }
    if (par == 0) *(float4*)(sP + c4) = acc;
    __syncthreads();
    if (par == 1) {
        float4 p = *(const float4*)(sP + c4);
        p.x += acc.x; p.y += acc.y; p.z += acc.z; p.w += acc.w;
        *(float4*)(F + OFF_PART + bid * DIM + c4) = p;
    }
}

// ---------------- K1b: pre-reduce 512 partial rows -> 8 ----------------------
__global__ __launch_bounds__(256) void k1b_red(float* __restrict__ F) {
    int bx = blockIdx.x;               // 16 blocks
    int orow = bx >> 1;
    int c = (bx & 1) * 256 + threadIdx.x;
    float s = 0.f;
    #pragma unroll 8
    for (int j = 0; j < 64; ++j)
        s += F[OFF_PART + (orow * 64 + j) * DIM + c];
    F[OFF_PRED + orow * DIM + c] = s;
}

// ---------------- K2: hypernet trunk (1 block) ----------
__global__ __launch_bounds__(256) void k2_hyper(
    const float* __restrict__ Wh1, const float* __restrict__ bh1,
    const float* __restrict__ g1,  const float* __restrict__ be1,
    const float* __restrict__ Wh2, const float* __restrict__ bh2,
    const float* __restrict__ g2,  const float* __restrict__ be2,
    const float* __restrict__ ensw, float* __restrict__ F)
{
    __shared__ __align__(16) float sctx[DIM];
    __shared__ __align__(16) float sh1[H1N];
    __shared__ __align__(16) float sh2[H2N];
    int t = threadIdx.x;

    if (t < 128) {
        int c4 = t * 4;
        float4 a = make_float4(0.f, 0.f, 0.f, 0.f);
        #pragma unroll
        for (int b = 0; b < 8; ++b) {
            float4 v = *(const float4*)(F + OFF_PRED + b * DIM + c4);
            a.x += v.x; a.y += v.y; a.z += v.z; a.w += v.w;
        }
        a.x *= (1.0f / BATCH); a.y *= (1.0f / BATCH);
        a.z *= (1.0f / BATCH); a.w *= (1.0f / BATCH);
        *(float4*)(sctx + c4) = a;
    }
    __syncthreads();

    if (t < H1N) {
        float v = bh1[t];
        const float4* w = (const float4*)(Wh1 + t * DIM);
        for (int k = 0; k < DIM / 4; ++k) {
            float4 ww = w[k]; float4 c = *(const float4*)(sctx + k * 4);
            v += ww.x * c.x + ww.y * c.y + ww.z * c.z + ww.w * c.w;
        }
        sh1[t] = v;
    }
    __syncthreads();
    {
        float mu = 0.f;
        for (int k = 0; k < H1N; ++k) mu += sh1[k];
        mu *= (1.0f / H1N);
        float var = 0.f;
        for (int k = 0; k < H1N; ++k) { float d = sh1[k] - mu; var += d * d; }
        var *= (1.0f / H1N);
        float inv = rsqrtf(var + 1e-5f);
        __syncthreads();
        if (t < H1N) {
            float v = (sh1[t] - mu) * inv * g1[t] + be1[t];
            sh1[t] = fmaxf(v, 0.f);
        }
        __syncthreads();
    }

    {
        float v = bh2[t];
        const float4* w = (const float4*)(Wh2 + t * H1N);
        for (int k = 0; k < H1N / 4; ++k) {
            float4 ww = w[k]; float4 c = *(const float4*)(sh1 + k * 4);
            v += ww.x * c.x + ww.y * c.y + ww.z * c.z + ww.w * c.w;
        }
        sh2[t] = v;
    }
    __syncthreads();
    {
        float mu = 0.f;
        for (int k = 0; k < H2N; ++k) mu += sh2[k];
        mu *= (1.0f / H2N);
        float var = 0.f;
        for (int k = 0; k < H2N; ++k) { float d = sh2[k] - mu; var += d * d; }
        var *= (1.0f / H2N);
        float inv = rsqrtf(var + 1e-5f);
        float v = (sh2[t] - mu) * inv * g2[t] + be2[t];
        F[OFF_H + t] = fmaxf(v, 0.f);
    }

    if (t == 0) {
        float m = -1e30f;
        for (int s = 0; s < NSUB; ++s) m = fmaxf(m, ensw[s]);
        float sum = 0.f, e[NSUB];
        for (int s = 0; s < NSUB; ++s) { e[s] = __expf(ensw[s] - m); sum += e[s]; }
        for (int s = 0; s < NSUB; ++s) F[OFF_W + s] = e[s] / sum;
    }
}

// ---------------- K3: persistent grid-stride GEMV + pack ---------------------
static __device__ __forceinline__ void k3_pack(float* F, int row, float val) {
    __hip_bfloat16* W1B = (__hip_bfloat16*)(F + OFF_W1B);
    __hip_bfloat16* W2B = (__hip_bfloat16*)(F + OFF_W2B);
    int s = row / TOTALP;
    int r = row - s * TOTALP;
    if (r < WS1P) {
        int hh = r >> 9, k = r & 511;
        W1B[(s * HID + hh) * DIM + k] = __float2bfloat16(val);
    } else if (r < WS1B1) {
        F[OFF_B1 + s * HID + (r - WS1P)] = val;
    } else if (r < WS2END) {
        int q = r - WS1B1; int c = q >> 5, hh = q & 31;
        float ws = F[OFF_W + s];
        W2B[c * NHID + s * HID + hh] = __float2bfloat16(ws * val);
    } else {
        F[OFF_B2R + s * NCLS + (r - WS2END)] = val;
    }
}

#define K3_NWAVE 8192
#define K3_STRIDE (K3_NWAVE * 2)      // 16384 rows per sweep

__global__ __launch_bounds__(256) void k3_gemv(
    const float* __restrict__ Wh3, const float* __restrict__ bh3, float* __restrict__ F)
{
    int t = threadIdx.x;
    int wid = t >> 6, lane = t & 63;
    int gw = blockIdx.x * 4 + wid;
    const float4 h = *(const float4*)(F + OFF_H + lane * 4);

    int row = gw * 2;
    float4 w0, w1;
    if (row < NPAR) {
        w0 = *(const float4*)(Wh3 + (size_t)row * 256 + lane * 4);
        w1 = *(const float4*)(Wh3 + (size_t)(row + 1) * 256 + lane * 4);
    }
    while (row < NPAR) {
        int nrow = row + K3_STRIDE;
        float4 n0, n1;
        if (nrow < NPAR) {
            n0 = *(const float4*)(Wh3 + (size_t)nrow * 256 + lane * 4);
            n1 = *(const float4*)(Wh3 + (size_t)(nrow + 1) * 256 + lane * 4);
        }
        float d0 = w0.x * h.x + w0.y * h.y + w0.z * h.z + w0.w * h.w;
        float d1 = w1.x * h.x + w1.y * h.y + w1.z * h.z + w1.w * h.w;
        #pragma unroll
        for (int off = 32; off; off >>= 1) {
            d0 += __shfl_down(d0, off);
            d1 += __shfl_down(d1, off);
        }
        if (lane == 0) {
            k3_pack(F, row,     d0 + bh3[row]);
            k3_pack(F, row + 1, d1 + bh3[row + 1]);
        }
        w0 = n0; w1 = n1;
        row = nrow;
    }
}

// ---------------- K5: fused dual GEMM, A-in-registers + T4 pipeline ----------
// (R18 best: 1x8 wave tile, afr[16], BK=64, counted vmcnt, 48 KB -> 3 blk/CU)
__global__ __launch_bounds__(256) void gemm_fused(
    const float* __restrict__ x, const __hip_bfloat16* __restrict__ W1B,
    const __hip_bfloat16* __restrict__ W2B, const float* __restrict__ F,
    float* __restrict__ out)
{
    __shared__ __align__(16) unsigned char sB[2][128 * 128];
    __shared__ __align__(16) unsigned char sP[64 * 256];
    const int t = threadIdx.x;
    int bid = blockIdx.x;
    const int cpx = gridDim.x >> 3;
    bid = (bid & 7) * cpx + (bid >> 3);
    const int Row0 = bid * 64;
    const int wid = t >> 6, lane = t & 63;
    const int l16 = lane & 15, lq = lane >> 4;

    f32x4 acc1[8], acc2[8];
    #pragma unroll
    for (int fn = 0; fn < 8; ++fn) acc2[fn] = (f32x4){0.f, 0.f, 0.f, 0.f};

    auto stageW1 = [&](int n1, int kc, int b) {
        #pragma unroll
        for (int i = 0; i < 4; ++i) {
            int cidx = wid * 4 + i;
            int ul = cidx * 64 + lane;
            int row = ul >> 3, u = ul & 7;
            gload16(W1B + (size_t)(n1 * 128 + row) * 512 + kc + ((u ^ (row & 7)) << 3),
                    &sB[b][cidx * 1024]);
        }
    };
    auto stageW2 = [&](int n1, int h, int b) {
        #pragma unroll
        for (int i = 0; i < 4; ++i) {
            int cidx = wid * 4 + i;
            int ul = cidx * 64 + lane;
            int row = ul >> 3, u = ul & 7;
            gload16(W2B + (size_t)row * NHID + n1 * 128 + h * 64 + ((u ^ (row & 7)) << 3),
                    &sB[b][cidx * 1024]);
        }
    };

    stageW1(0, 0, 0);

    short8 afr[16];                    // A fragments, whole K; 64 VGPR
    {
        const float* xrow = x + (size_t)(Row0 + wid * 16 + l16) * 512;
        #pragma unroll
        for (int i = 0; i < 16; ++i) { // i = st*2+kk ; k0 = st*64+kk*32+lq*8
            int k0 = (i >> 1) * 64 + (i & 1) * 32 + lq * 8;
            float4 a = *(const float4*)(xrow + k0);
            float4 b = *(const float4*)(xrow + k0 + 4);
            unsigned int p[4];
            p[0] = (unsigned)f2bf(a.x) | ((unsigned)f2bf(a.y) << 16);
            p[1] = (unsigned)f2bf(a.z) | ((unsigned)f2bf(a.w) << 16);
            p[2] = (unsigned)f2bf(b.x) | ((unsigned)f2bf(b.y) << 16);
            p[3] = (unsigned)f2bf(b.z) | ((unsigned)f2bf(b.w) << 16);
            afr[i] = *(short8*)p;
        }
    }
    asm volatile("s_waitcnt vmcnt(0)" ::: "memory");
    __builtin_amdgcn_s_barrier();

    auto comp1 = [&](int st, int b) {
        #pragma unroll
        for (int kk = 0; kk < 2; ++kk) {
            int u = kk * 4 + lq;
            short8 af = afr[st * 2 + kk];
            short8 bfv[8];
            #pragma unroll
            for (int fn = 0; fn < 8; ++fn) {
                int rw = fn * 16 + l16;
                bfv[fn] = *(const short8*)(&sB[b][rw * 128 + ((u ^ (rw & 7)) << 4)]);
            }
            #pragma unroll
            for (int fn = 0; fn < 8; ++fn)
                acc1[fn] = __builtin_amdgcn_mfma_f32_16x16x32_bf16(
                    af, bfv[fn], acc1[fn], 0, 0, 0);
        }
    };
    auto comp2 = [&](int h, int b) {
        #pragma unroll
        for (int kk = 0; kk < 2; ++kk) {
            int u = kk * 4 + lq;
            int punit = (h * 2 + kk) * 4 + lq;
            int arow = wid * 16 + l16;
            short8 af = *(const short8*)(&sP[arow * 256 + ((punit ^ (arow & 7)) << 4)]);
            short8 bfv[8];
            #pragma unroll
            for (int fn = 0; fn < 8; ++fn) {
                int rw = fn * 16 + l16;
                bfv[fn] = *(const short8*)(&sB[b][rw * 128 + ((u ^ (rw & 7)) << 4)]);
            }
            #pragma unroll
            for (int fn = 0; fn < 8; ++fn)
                acc2[fn] = __builtin_amdgcn_mfma_f32_16x16x32_bf16(
                    af, bfv[fn], acc2[fn], 0, 0, 0);
        }
    };

    int buf = 0;
    float b1r[8];
    for (int n1 = 0; n1 < 5; ++n1) {
        #pragma unroll
        for (int st = 0; st < 10; ++st) {
            if (st < 9) {
                if (st + 1 < 8) stageW1(n1, (st + 1) * 64, buf ^ 1);
                else stageW2(n1, st + 1 - 8, buf ^ 1);
            } else if (n1 < 4) {
                stageW1(n1 + 1, 0, buf ^ 1);
            }
            if (st == 9 && n1 == 4)
                asm volatile("s_waitcnt vmcnt(0)" ::: "memory");
            else
                asm volatile("s_waitcnt vmcnt(4)" ::: "memory");
            __builtin_amdgcn_s_barrier();
            __builtin_amdgcn_sched_barrier(0);

            if (st == 0) {
                #pragma unroll
                for (int fn = 0; fn < 8; ++fn) {
                    acc1[fn] = (f32x4){0.f, 0.f, 0.f, 0.f};
                    b1r[fn] = F[OFF_B1 + n1 * 128 + fn * 16 + l16];
                }
            }
            if (st < 8) comp1(st, buf);
            else comp2(st - 8, buf);
            if (st == 7) {
                #pragma unroll
                for (int fn = 0; fn < 8; ++fn) {
                    int col = fn * 16 + l16;
                    int unit = col >> 3;
                    #pragma unroll
                    for (int r = 0; r < 4; ++r) {
                        int row = wid * 16 + lq * 4 + r;
                        float v = fmaxf(acc1[fn][r] + b1r[fn], 0.f);
                        *(unsigned short*)(&sP[row * 256 + ((unit ^ (row & 7)) << 4)
                                           + (col & 7) * 2]) = f2bf(v);
                    }
                }
            }
            __builtin_amdgcn_sched_barrier(0);
            __builtin_amdgcn_s_barrier();
            buf ^= 1;
        }
    }

    float* sBe = (float*)sP;
    if (t < 128) {
        float b = 0.f;
        if (t < NCLS) {
            #pragma unroll
            for (int s = 0; s < NSUB; ++s)
                b += F[OFF_W + s] * F[OFF_B2R + s * NCLS + t];
        }
        sBe[t] = b;
    }
    __syncthreads();

    #pragma unroll
    for (int fn = 0; fn < 8; ++fn) {
        int gcol = fn * 16 + l16;
        if (gcol < NCLS) {
            float be = sBe[gcol];
            #pragma unroll
            for (int r = 0; r < 4; ++r) {
                int grow = Row0 + wid * 16 + lq * 4 + r;
                out[(size_t)grow * NCLS + gcol] = acc2[fn][r] + be;
            }
        }
    }
}

// ---------------- launch ----------------
extern "C" void kernel_launch(void* const* d_in, const int* in_sizes, int n_in,
                              void* d_out, int out_size, void* d_ws, size_t ws_size,
                              hipStream_t stream)
{
    const float* x    = (const float*)d_in[0];
    const float* Wh1  = (const float*)d_in[1];
    const float* bh1  = (const float*)d_in[2];
    const float* g1   = (const float*)d_in[3];
    const float* be1  = (const float*)d_in[4];
    const float* Wh2  = (const float*)d_in[5];
    const float* bh2  = (const float*)d_in[6];
    const float* g2   = (const float*)d_in[7];
    const float* be2  = (const float*)d_in[8];
    const float* Wh3  = (const float*)d_in[9];
    const float* bh3  = (const float*)d_in[10];
    const float* ensw = (const float*)d_in[11];
    float* F = (float*)d_ws;
    float* out = (float*)d_out;

    const __hip_bfloat16* W1B = (const __hip_bfloat16*)(F + OFF_W1B);
    const __hip_bfloat16* W2B = (const __hip_bfloat16*)(F + OFF_W2B);

    k1_colsum<<<512, 256, 0, stream>>>(x, F);
    k1b_red<<<16, 256, 0, stream>>>(F);
    k2_hyper<<<1, 256, 0, stream>>>(Wh1, bh1, g1, be1, Wh2, bh2, g2, be2, ensw, F);
    k3_gemv<<<2048, 256, 0, stream>>>(Wh3, bh3, F);
    // fused: out = relu(x@W1^T+b1) @ W2^T + be   M=32768, grid 512 x BM=64
    gemm_fused<<<BATCH / 64, 256, 0, stream>>>(x, W1B, W2B, F, out);
}